// Round 5
// baseline (470.536 us; speedup 1.0000x reference)
//
#include <hip/hip_runtime.h>
#include <hip/hip_bf16.h>
#include <cstdint>
#include <cstddef>

#define C_IN 768
#define HW 120
#define WP 122
#define PIX (HW*HW)       // 14400
#define PPIX (WP*WP)      // 14884
#define S_CH 48
#define CCH 256           // channel chunk for transpose
#define LSTR 257          // LDS row stride (ushorts), 257 % 32 == 1 -> conflict-free

// ws layout (bytes)
#define OFF_POOL 0                    // 768*51*4 = 156672
#define OFF_HDD3 163840               // 48 floats
#define OFF_WT   262144               // 9*768*768*2 = 10616832
#define OFF_XTP  10878976             // 14884*768*2 = 22861824 ; end ~33.7MB

typedef __attribute__((ext_vector_type(8))) short short8;
typedef __attribute__((ext_vector_type(4))) float floatx4;
typedef __attribute__((ext_vector_type(4))) uint uint4v;

#define AS3(p) ((__attribute__((address_space(3))) uint*)(p))
#define AS1(p) ((const __attribute__((address_space(1))) uint*)(p))

__device__ inline ushort f2bf(float f) {
  union { float f; uint i; } v; v.f = f;
  uint r = v.i + 0x7FFF + ((v.i >> 16) & 1);   // round-to-nearest-even
  return (ushort)(r >> 16);
}

// PyTorch bicubic(3->5), a=-0.75, align_corners=False, border-replicate
__device__ __constant__ float M35[5][3] = {
  { 1.096f, -0.096f,  0.000f },
  { 0.612f,  0.460f, -0.072f },
  { 0.000f,  1.000f,  0.000f },
  {-0.072f,  0.460f,  0.612f },
  { 0.000f, -0.096f,  1.096f },
};

// ---------------- K0: zero-pad + transpose x (C,H,W) f32 -> xTp (122*122, C) bf16 ----
__global__ __launch_bounds__(256) void k_pad_transpose(const float* __restrict__ x,
                                                       ushort* __restrict__ xTp) {
  int ph = blockIdx.x;          // padded row 0..121
  int c0 = blockIdx.y * CCH;    // 0, 256, 512
  int tid = threadIdx.x;
  ushort* rowbase = xTp + (size_t)ph * WP * C_IN;
  if (ph == 0 || ph == WP - 1) {
    uint4v z = {0, 0, 0, 0};
    for (int i = tid; i < WP * (CCH / 8); i += 256) {
      int w = i / (CCH / 8), j = i % (CCH / 8);
      *(uint4v*)&rowbase[(size_t)w * C_IN + c0 + j * 8] = z;
    }
    return;
  }
  int h = ph - 1;
  __shared__ ushort T[HW * LSTR];   // 120*257*2 = 61680 B
  int wave = tid >> 6, lane = tid & 63;
  for (int k = 0; k < 64; k++) {
    int cl = wave * 64 + k;                       // local channel 0..255
    const float* src = x + (size_t)(c0 + cl) * PIX + h * HW;
    if (lane < 60) {
      float vx = src[2 * lane], vy = src[2 * lane + 1];
      T[(2 * lane) * LSTR + cl]     = f2bf(vx);
      T[(2 * lane + 1) * LSTR + cl] = f2bf(vy);
    }
  }
  __syncthreads();
  if (tid < 128) {
    *(uint*)&rowbase[c0 + 2 * tid] = 0;
    *(uint*)&rowbase[(size_t)(WP - 1) * C_IN + c0 + 2 * tid] = 0;
  }
  for (int idx = tid; idx < HW * (CCH / 2); idx += 256) {
    int w = idx >> 7, pr = idx & 127;
    uint a = T[w * LSTR + 2 * pr];
    uint b = T[w * LSTR + 2 * pr + 1];
    *(uint*)&rowbase[(size_t)(1 + w) * C_IN + c0 + 2 * pr] = a | (b << 16);
  }
}

// ---------------- K1: pooling per channel: a1, a3u (bicubic), a5 -> pooled[c][51] -----
// R4: tail parallelized (was serial on tid==0).
__global__ __launch_bounds__(256) void k_pool(const float* __restrict__ x,
                                              float* __restrict__ pooled) {
  int c = blockIdx.x;
  int tid = threadIdx.x;
  __shared__ float fine[225];   // 15x15 grid of 8x8 block sums
  __shared__ float s3[9], a3v[9], a5v[25];
  if (tid < 225) {
    int fr = tid / 15, fc = tid % 15;
    const float* base = x + (size_t)c * PIX + fr * 8 * HW + fc * 8;
    float s = 0.f;
#pragma unroll
    for (int r = 0; r < 8; r++) {
      floatx4 a = *(const floatx4*)(base + r * HW);
      floatx4 b = *(const floatx4*)(base + r * HW + 4);
#pragma unroll
      for (int j = 0; j < 4; j++) s += a[j] + b[j];
    }
    fine[tid] = s;
  }
  __syncthreads();
  if (tid < 9) {
    int i = tid / 3, j = tid % 3;
    float s = 0.f;
    for (int a = 0; a < 5; a++) for (int b = 0; b < 5; b++) s += fine[(i*5+a)*15 + j*5+b];
    s3[tid] = s; a3v[tid] = s / 1600.f;
  } else if (tid >= 32 && tid < 57) {
    int t = tid - 32; int p = t / 5, q = t % 5;
    float s = 0.f;
    for (int a = 0; a < 3; a++) for (int b = 0; b < 3; b++) s += fine[(p*3+a)*15 + q*3+b];
    a5v[t] = s / 576.f;
  }
  __syncthreads();
  float* out = pooled + c * 51;
  if (tid == 63) {
    float tot = 0.f;
    for (int k = 0; k < 9; k++) tot += s3[k];
    out[0] = tot / 14400.f;
  }
  if (tid < 25) {
    int p = tid / 5, q = tid % 5;
    float s = 0.f;
    for (int i = 0; i < 3; i++) for (int j = 0; j < 3; j++)
      s += M35[p][i] * M35[q][j] * a3v[i*3+j];
    out[1 + tid] = s;
    out[26 + tid] = a5v[tid];
  }
}

// ---------------- K2: routing MLP -> hdd3[48] ----------------------------------------
__global__ __launch_bounds__(256) void k_route(const float* __restrict__ pooled,
                                               const float* __restrict__ w_pw1,
                                               const float* __restrict__ w_dw1,
                                               const float* __restrict__ w_dw2,
                                               float* __restrict__ hdd3) {
  int s = blockIdx.x;  // 0..47
  int tid = threadIdx.x;
  __shared__ float red[26][256];
  float acc[25]; float accw1 = 0.f;
#pragma unroll
  for (int q = 0; q < 25; q++) acc[q] = 0.f;
  for (int c = tid; c < C_IN; c += 256) {
    const float* pl = pooled + c * 51;
    float w1 = w_pw1[(size_t)s * 3 * C_IN + c];
    float w2 = w_pw1[(size_t)s * 3 * C_IN + C_IN + c];
    float w3 = w_pw1[(size_t)s * 3 * C_IN + 2 * C_IN + c];
    accw1 += w1 * pl[0];
#pragma unroll
    for (int q = 0; q < 25; q++) acc[q] += w2 * pl[1 + q] + w3 * pl[26 + q];
  }
#pragma unroll
  for (int q = 0; q < 25; q++) red[q][tid] = acc[q];
  red[25][tid] = accw1;
  for (int st = 128; st; st >>= 1) {
    __syncthreads();
    if (tid < st)
      for (int q = 0; q < 26; q++) red[q][tid] += red[q][tid + st];
  }
  __syncthreads();
  if (tid == 0) {
    float hdd[5][5];
    for (int p = 0; p < 5; p++) for (int q = 0; q < 5; q++) {
      float v = red[p*5+q][0] + red[25][0];
      hdd[p][q] = v > 0.f ? v : 0.f;
    }
    float wd1[9], wd2[9];
    for (int i = 0; i < 9; i++) { wd1[i] = w_dw1[s*9 + i]; wd2[i] = w_dw2[s*9 + i]; }
    float h2[3][3];
    for (int i = 0; i < 3; i++) for (int j = 0; j < 3; j++) {
      float v = 0.f;
      for (int u = 0; u < 3; u++) for (int vv = 0; vv < 3; vv++) v += wd1[u*3+vv] * hdd[i+u][j+vv];
      h2[i][j] = v > 0.f ? v : 0.f;
    }
    float v = 0.f;
    for (int u = 0; u < 3; u++) for (int vv = 0; vv < 3; vv++) v += wd2[u*3+vv] * h2[u][vv];
    hdd3[s] = v > 0.f ? v : 0.f;
  }
}

// ---------------- K3: gates + weight synthesis -> wt[tap][o][c] (bf16) ---------------
__global__ __launch_bounds__(256) void k_wt(const float* __restrict__ convs,
                                            const float* __restrict__ w_pw2,
                                            const float* __restrict__ hdd3,
                                            ushort* __restrict__ wt) {
  int o = blockIdx.x;  // 0..767
  int tid = threadIdx.x;
  __shared__ float g[3];
  __shared__ __align__(16) ushort st[9 * C_IN];   // 13824 B
  if (tid < 3) {
    float v = 0.f;
    for (int s = 0; s < S_CH; s++)
      v += w_pw2[((size_t)tid * C_IN + o) * S_CH + s] * hdd3[s];
    g[tid] = 1.f / (1.f + __expf(-v));
  }
  __syncthreads();
  float g0 = g[0], g1 = g[1], g2 = g[2];
  const float* c0p = convs + (size_t)o * 6912;
  const float* c1p = convs + (size_t)(C_IN + o) * 6912;
  const float* c2p = convs + (size_t)(2 * C_IN + o) * 6912;
  for (int i = tid * 4; i < 6912; i += 1024) {
    floatx4 a = *(const floatx4*)(c0p + i);
    floatx4 b = *(const floatx4*)(c1p + i);
    floatx4 c = *(const floatx4*)(c2p + i);
#pragma unroll
    for (int j = 0; j < 4; j++) {
      int idx = i + j;
      int cch = idx / 9, tap = idx - cch * 9;
      st[tap * C_IN + cch] = f2bf(g0 * a[j] + g1 * b[j] + g2 * c[j]);
    }
  }
  __syncthreads();
  for (int i = tid; i < 864; i += 256) {        // 864 = 9*768/8 chunks of 16B
    int tap = i / 96, j = i - tap * 96;
    *(uint4v*)&wt[((size_t)(tap * C_IN + o)) * C_IN + j * 8] =
        *(const uint4v*)&st[tap * C_IN + j * 8];
  }
}

// ---------------- K4: main conv, MFMA 16x16x32 bf16 ----------------------------------
// R4 (resubmit; prior run was an infra failure): depth-2 counted-vmcnt pipeline,
// ROLLED loop (I$-clean), m201 2-barrier phase.
//   phase g: [stage B(g+3) (+A at tap0)][s_waitcnt vmcnt(N) certify B(g+1), issued g-2]
//            [s_barrier][fence][ds_read frags(g+1)][16 MFMA frags(g)][fence][s_barrier]
//   * 3 B buffers, buf = tap%3 (static: 9%3==0); stage-ahead-3 -> 2-phase latency cover
//   * WAR on buffer reuse: tenant B(g)'s frags read at g-1 BEFORE barrier2(g-1);
//     overwrite-issue at g is after it -> safe with the second barrier
//   * vmcnt ledger: steady N=4 (2 B-groups in flight); N=7 on the 3 phases where the
//     A-union load rides; tail 2,0; one vmcnt(0) in prologue only
//   * loop rolled over cc-pairs (18-phase body ~6KB, fits I$); cc22 + cc23 peeled
#define WAITV(N) asm volatile("s_waitcnt vmcnt(" #N ")" ::: "memory")
#define FENCE()  asm volatile("" ::: "memory")

#define READS(KH1, KW1, AI, BB, NX) do {                                        \
    _Pragma("unroll")                                                           \
    for (int nt = 0; nt < 4; nt++) NX##_b[nt] = *(const short8*)&Bt[BB][b_rd[nt]]; \
    _Pragma("unroll")                                                           \
    for (int mt = 0; mt < 4; mt++) {                                            \
      int p_ = P0[mt] + ((KH1) * 18 + (KW1));                                   \
      int idx_ = p_ * 32 + ((quad ^ ((p_ >> 1) & 3)) << 3);                     \
      NX##_a[mt] = *(const short8*)&Aun[AI][idx_];                              \
    }                                                                           \
  } while (0)

#define MFMAS(CS) do {                                                          \
    __builtin_amdgcn_s_setprio(1);                                              \
    _Pragma("unroll")                                                           \
    for (int mt = 0; mt < 4; mt++)                                              \
      _Pragma("unroll")                                                         \
      for (int nt = 0; nt < 4; nt++)                                            \
        acc[mt][nt] = __builtin_amdgcn_mfma_f32_16x16x32_bf16(CS##_a[mt], CS##_b[nt], \
                                                              acc[mt][nt], 0, 0, 0); \
    __builtin_amdgcn_s_setprio(0);                                              \
  } while (0)

#define PH(STAGES, WN, KH1, KW1, AI, BB, CS, NS) do {                           \
    STAGES;                                                                     \
    WAITV(WN);                                                                  \
    __builtin_amdgcn_s_barrier();                                               \
    FENCE();                                                                    \
    READS(KH1, KW1, AI, BB, NS);                                                \
    MFMAS(CS);                                                                  \
    FENCE();                                                                    \
    __builtin_amdgcn_s_barrier();                                               \
  } while (0)

// steady 9-phase cc body: stage B(tap+3); A(cc+1) rides at tap0.
// sets alternate S,T,... (9 phases -> exits flipped)
#define CCHALF(cc, AIC, AIN, S, T) do {                                         \
    PH({ stageB(cc, 3, 0); stageA((cc)+1, AIN); }, 7, 0, 1, AIC, 1, S, T);      \
    PH({ stageB(cc, 4, 1); },                      7, 0, 2, AIC, 2, T, S);      \
    PH({ stageB(cc, 5, 2); },                      7, 1, 0, AIC, 0, S, T);      \
    PH({ stageB(cc, 6, 0); },                      4, 1, 1, AIC, 1, T, S);      \
    PH({ stageB(cc, 7, 1); },                      4, 1, 2, AIC, 2, S, T);      \
    PH({ stageB(cc, 8, 2); },                      4, 2, 0, AIC, 0, T, S);      \
    PH({ stageB((cc)+1, 0, 0); },                  4, 2, 1, AIC, 1, S, T);      \
    PH({ stageB((cc)+1, 1, 1); },                  4, 2, 2, AIC, 2, T, S);      \
    PH({ stageB((cc)+1, 2, 2); },                  4, 0, 0, AIN, 0, S, T);      \
  } while (0)

// cc=23 tail: no A, no next-cc B; N ramps 4..4,2,0; last phase MFMA-only.
#define CCTAIL(AIC, S, T) do {                                                  \
    PH({ stageB(23, 3, 0); }, 4, 0, 1, AIC, 1, S, T);                           \
    PH({ stageB(23, 4, 1); }, 4, 0, 2, AIC, 2, T, S);                           \
    PH({ stageB(23, 5, 2); }, 4, 1, 0, AIC, 0, S, T);                           \
    PH({ stageB(23, 6, 0); }, 4, 1, 1, AIC, 1, T, S);                           \
    PH({ stageB(23, 7, 1); }, 4, 1, 2, AIC, 2, S, T);                           \
    PH({ stageB(23, 8, 2); }, 4, 2, 0, AIC, 0, T, S);                           \
    PH({ ; },                 2, 2, 1, AIC, 1, S, T);                           \
    PH({ ; },                 0, 2, 2, AIC, 2, T, S);                           \
    MFMAS(S);                                                                   \
  } while (0)

__global__ __launch_bounds__(256) void k_conv(const ushort* __restrict__ xTp,
                                              const ushort* __restrict__ wt,
                                              float* __restrict__ y) {
  __shared__ __align__(16) ushort Aun[2][768 * 8];   // 2 x 12288 B
  __shared__ __align__(16) ushort Bt[3][512 * 8];    // 3 x  8192 B  (48 KiB total)
  int tid = threadIdx.x;
  int lane = tid & 63;
  int quad = lane >> 4, l15 = lane & 15;
  int wave = tid >> 6;
  int wave_m = wave >> 1, wave_n = wave & 1;

  // XCD-chunked bijective swizzle (720 % 8 == 0); wg = n_t*120 + m_t
  int bid = blockIdx.x;
  int wg = (bid & 7) * 90 + (bid >> 3);
  int n_t = wg / 120, m_t = wg - n_t * 120;
  int h0 = (m_t >> 3) << 3;    // 0..112 step 8
  int w0 = (m_t & 7) << 4;     // 0..112 step 16 (cols >=120 discarded)
  int n0 = n_t << 7;

  // A staging: slot t holds union pixel p=t>>2, source sub s=(t&3)^((p>>1)&3)
  size_t a_off[3];
#pragma unroll
  for (int r = 0; r < 3; r++) {
    int t = r * 256 + tid;
    int p = t >> 2; if (p > 179) p = 179;
    int sl = (t & 3) ^ ((p >> 1) & 3);
    int pr = p / 18, pc = p - pr * 18;             // union is 10 rows x 18 cols
    int pix = (h0 + pr) * WP + (w0 + pc);
    if (pix > PPIX - 1) pix = PPIX - 1;            // clamp: only affects discarded outputs
    a_off[r] = (size_t)pix * C_IN + sl * 8;
  }
  // B staging: slot t -> row n=t>>2, source sub s=(t&3)^((n>>1)&3)
  size_t b_off[2];
#pragma unroll
  for (int r = 0; r < 2; r++) {
    int t = r * 256 + tid;
    int n = t >> 2;
    int sl = (t & 3) ^ ((n >> 1) & 3);
    b_off[r] = (size_t)(n0 + n) * C_IN + sl * 8;
  }
  int b_rd[4];
#pragma unroll
  for (int nt = 0; nt < 4; nt++) {
    int n = wave_n * 64 + nt * 16 + l15;
    b_rd[nt] = n * 32 + ((quad ^ ((n >> 1) & 3)) << 3);
  }
  int amh = wave_m * 4;
  int P0[4];
#pragma unroll
  for (int mt = 0; mt < 4; mt++) P0[mt] = (amh + mt) * 18 + l15;

  auto stageA = [&](int ncc, int na) {
#pragma unroll
    for (int r = 0; r < 3; r++)
      __builtin_amdgcn_global_load_lds(AS1(xTp + a_off[r] + ncc * 32),
                                       AS3(&Aun[na][(r * 256 + wave * 64) * 8]), 16, 0, 0);
  };
  auto stageB = [&](int ncc, int ntap, int nb) {
    const ushort* wb = wt + (size_t)ntap * C_IN * C_IN + ncc * 32;
#pragma unroll
    for (int r = 0; r < 2; r++)
      __builtin_amdgcn_global_load_lds(AS1(wb + b_off[r]),
                                       AS3(&Bt[nb][(r * 256 + wave * 64) * 8]), 16, 0, 0);
  };

  floatx4 acc[4][4];
#pragma unroll
  for (int i = 0; i < 4; i++)
#pragma unroll
    for (int j = 0; j < 4; j++) acc[i][j] = (floatx4){0.f, 0.f, 0.f, 0.f};

  // fragment sets (static names only -> stay in VGPRs)
  short8 sa_a[4], sa_b[4], sb_a[4], sb_b[4];

  // prologue: B(0,0/1/2) -> bufs 0/1/2, A(0) -> Aun0; drain once; read frags(tap0);
  // barrier2 so the loop's first overwrite of buf0 can't race any wave's reads.
  stageB(0, 0, 0);
  stageB(0, 1, 1);
  stageB(0, 2, 2);
  stageA(0, 0);
  WAITV(0);
  __builtin_amdgcn_s_barrier();
  FENCE();
  READS(0, 0, 0, 0, sa);           // frags for tap0 of cc0
  FENCE();
  __builtin_amdgcn_s_barrier();

  for (int cc = 0; cc < 22; cc += 2) {
    CCHALF(cc,     0, 1, sa, sb);
    CCHALF(cc + 1, 1, 0, sb, sa);
  }
  CCHALF(22, 0, 1, sa, sb);
  CCTAIL(1, sb, sa);

  // epilogue: D layout col(n)=lane&15, row(m)=quad*4+reg
#pragma unroll
  for (int mt = 0; mt < 4; mt++) {
    int h = h0 + wave_m * 4 + mt;
    int wbase = w0 + quad * 4;
    if (wbase < HW) {
#pragma unroll
      for (int nt = 0; nt < 4; nt++) {
        int n = n0 + wave_n * 64 + nt * 16 + l15;
        *(floatx4*)&y[(size_t)n * PIX + h * HW + wbase] = acc[mt][nt];
      }
    }
  }
}

extern "C" void kernel_launch(void* const* d_in, const int* in_sizes, int n_in,
                              void* d_out, int out_size, void* d_ws, size_t ws_size,
                              hipStream_t stream) {
  const float* x     = (const float*)d_in[0];
  const float* convs = (const float*)d_in[1];
  const float* w_pw1 = (const float*)d_in[2];
  const float* w_dw1 = (const float*)d_in[3];
  const float* w_dw2 = (const float*)d_in[4];
  const float* w_pw2 = (const float*)d_in[5];
  float* y = (float*)d_out;
  char* ws = (char*)d_ws;
  float*  pooled = (float*)(ws + OFF_POOL);
  float*  hdd3   = (float*)(ws + OFF_HDD3);
  ushort* wt     = (ushort*)(ws + OFF_WT);
  ushort* xTp    = (ushort*)(ws + OFF_XTP);

  hipLaunchKernelGGL(k_pad_transpose, dim3(122, 3), dim3(256), 0, stream, x, xTp);
  hipLaunchKernelGGL(k_pool,          dim3(768),    dim3(256), 0, stream, x, pooled);
  hipLaunchKernelGGL(k_route,         dim3(48),     dim3(256), 0, stream, pooled, w_pw1, w_dw1, w_dw2, hdd3);
  hipLaunchKernelGGL(k_wt,            dim3(768),    dim3(256), 0, stream, convs, w_pw2, hdd3, wt);
  hipLaunchKernelGGL(k_conv,          dim3(720),    dim3(256), 0, stream, xTp, wt, y);
}

// Round 6
// 410.944 us; speedup vs baseline: 1.1450x; 1.1450x over previous
//
#include <hip/hip_runtime.h>
#include <hip/hip_bf16.h>
#include <cstdint>
#include <cstddef>

#define C_IN 768
#define HW 120
#define WP 122
#define PIX (HW*HW)       // 14400
#define PPIX (WP*WP)      // 14884
#define S_CH 48
#define CCH 256           // channel chunk for transpose
#define LSTR 257          // LDS row stride (ushorts), 257 % 32 == 1 -> conflict-free

// ws layout (bytes)
#define OFF_POOL 0                    // 768*51*4 = 156672
#define OFF_HDD3 163840               // 48 floats
#define OFF_WT   262144               // 9*768*768*2 = 10616832
#define OFF_XTP  10878976             // 14884*768*2 = 22861824 ; end ~33.7MB

typedef __attribute__((ext_vector_type(8))) short short8;
typedef __attribute__((ext_vector_type(4))) float floatx4;
typedef __attribute__((ext_vector_type(4))) uint uint4v;

#define AS3(p) ((__attribute__((address_space(3))) uint*)(p))
#define AS1(p) ((const __attribute__((address_space(1))) uint*)(p))

__device__ inline ushort f2bf(float f) {
  union { float f; uint i; } v; v.f = f;
  uint r = v.i + 0x7FFF + ((v.i >> 16) & 1);   // round-to-nearest-even
  return (ushort)(r >> 16);
}

// PyTorch bicubic(3->5), a=-0.75, align_corners=False, border-replicate
__device__ __constant__ float M35[5][3] = {
  { 1.096f, -0.096f,  0.000f },
  { 0.612f,  0.460f, -0.072f },
  { 0.000f,  1.000f,  0.000f },
  {-0.072f,  0.460f,  0.612f },
  { 0.000f, -0.096f,  1.096f },
};

// ---------------- K0: zero-pad + transpose x (C,H,W) f32 -> xTp (122*122, C) bf16 ----
__global__ __launch_bounds__(256) void k_pad_transpose(const float* __restrict__ x,
                                                       ushort* __restrict__ xTp) {
  int ph = blockIdx.x;          // padded row 0..121
  int c0 = blockIdx.y * CCH;    // 0, 256, 512
  int tid = threadIdx.x;
  ushort* rowbase = xTp + (size_t)ph * WP * C_IN;
  if (ph == 0 || ph == WP - 1) {
    uint4v z = {0, 0, 0, 0};
    for (int i = tid; i < WP * (CCH / 8); i += 256) {
      int w = i / (CCH / 8), j = i % (CCH / 8);
      *(uint4v*)&rowbase[(size_t)w * C_IN + c0 + j * 8] = z;
    }
    return;
  }
  int h = ph - 1;
  __shared__ ushort T[HW * LSTR];   // 120*257*2 = 61680 B
  int wave = tid >> 6, lane = tid & 63;
  for (int k = 0; k < 64; k++) {
    int cl = wave * 64 + k;                       // local channel 0..255
    const float* src = x + (size_t)(c0 + cl) * PIX + h * HW;
    if (lane < 60) {
      float vx = src[2 * lane], vy = src[2 * lane + 1];
      T[(2 * lane) * LSTR + cl]     = f2bf(vx);
      T[(2 * lane + 1) * LSTR + cl] = f2bf(vy);
    }
  }
  __syncthreads();
  if (tid < 128) {
    *(uint*)&rowbase[c0 + 2 * tid] = 0;
    *(uint*)&rowbase[(size_t)(WP - 1) * C_IN + c0 + 2 * tid] = 0;
  }
  for (int idx = tid; idx < HW * (CCH / 2); idx += 256) {
    int w = idx >> 7, pr = idx & 127;
    uint a = T[w * LSTR + 2 * pr];
    uint b = T[w * LSTR + 2 * pr + 1];
    *(uint*)&rowbase[(size_t)(1 + w) * C_IN + c0 + 2 * pr] = a | (b << 16);
  }
}

// ---------------- K1: pooling per channel: a1, a3u (bicubic), a5 -> pooled[c][51] -----
__global__ __launch_bounds__(256) void k_pool(const float* __restrict__ x,
                                              float* __restrict__ pooled) {
  int c = blockIdx.x;
  int tid = threadIdx.x;
  __shared__ float fine[225];   // 15x15 grid of 8x8 block sums
  __shared__ float s3[9], a3v[9], a5v[25];
  if (tid < 225) {
    int fr = tid / 15, fc = tid % 15;
    const float* base = x + (size_t)c * PIX + fr * 8 * HW + fc * 8;
    float s = 0.f;
#pragma unroll
    for (int r = 0; r < 8; r++) {
      floatx4 a = *(const floatx4*)(base + r * HW);
      floatx4 b = *(const floatx4*)(base + r * HW + 4);
#pragma unroll
      for (int j = 0; j < 4; j++) s += a[j] + b[j];
    }
    fine[tid] = s;
  }
  __syncthreads();
  if (tid < 9) {
    int i = tid / 3, j = tid % 3;
    float s = 0.f;
    for (int a = 0; a < 5; a++) for (int b = 0; b < 5; b++) s += fine[(i*5+a)*15 + j*5+b];
    s3[tid] = s; a3v[tid] = s / 1600.f;
  } else if (tid >= 32 && tid < 57) {
    int t = tid - 32; int p = t / 5, q = t % 5;
    float s = 0.f;
    for (int a = 0; a < 3; a++) for (int b = 0; b < 3; b++) s += fine[(p*3+a)*15 + q*3+b];
    a5v[t] = s / 576.f;
  }
  __syncthreads();
  float* out = pooled + c * 51;
  if (tid == 63) {
    float tot = 0.f;
    for (int k = 0; k < 9; k++) tot += s3[k];
    out[0] = tot / 14400.f;
  }
  if (tid < 25) {
    int p = tid / 5, q = tid % 5;
    float s = 0.f;
    for (int i = 0; i < 3; i++) for (int j = 0; j < 3; j++)
      s += M35[p][i] * M35[q][j] * a3v[i*3+j];
    out[1 + tid] = s;
    out[26 + tid] = a5v[tid];
  }
}

// ---------------- K2: routing MLP -> hdd3[48] ----------------------------------------
__global__ __launch_bounds__(256) void k_route(const float* __restrict__ pooled,
                                               const float* __restrict__ w_pw1,
                                               const float* __restrict__ w_dw1,
                                               const float* __restrict__ w_dw2,
                                               float* __restrict__ hdd3) {
  int s = blockIdx.x;  // 0..47
  int tid = threadIdx.x;
  __shared__ float red[26][256];
  float acc[25]; float accw1 = 0.f;
#pragma unroll
  for (int q = 0; q < 25; q++) acc[q] = 0.f;
  for (int c = tid; c < C_IN; c += 256) {
    const float* pl = pooled + c * 51;
    float w1 = w_pw1[(size_t)s * 3 * C_IN + c];
    float w2 = w_pw1[(size_t)s * 3 * C_IN + C_IN + c];
    float w3 = w_pw1[(size_t)s * 3 * C_IN + 2 * C_IN + c];
    accw1 += w1 * pl[0];
#pragma unroll
    for (int q = 0; q < 25; q++) acc[q] += w2 * pl[1 + q] + w3 * pl[26 + q];
  }
#pragma unroll
  for (int q = 0; q < 25; q++) red[q][tid] = acc[q];
  red[25][tid] = accw1;
  for (int st = 128; st; st >>= 1) {
    __syncthreads();
    if (tid < st)
      for (int q = 0; q < 26; q++) red[q][tid] += red[q][tid + st];
  }
  __syncthreads();
  if (tid == 0) {
    float hdd[5][5];
    for (int p = 0; p < 5; p++) for (int q = 0; q < 5; q++) {
      float v = red[p*5+q][0] + red[25][0];
      hdd[p][q] = v > 0.f ? v : 0.f;
    }
    float wd1[9], wd2[9];
    for (int i = 0; i < 9; i++) { wd1[i] = w_dw1[s*9 + i]; wd2[i] = w_dw2[s*9 + i]; }
    float h2[3][3];
    for (int i = 0; i < 3; i++) for (int j = 0; j < 3; j++) {
      float v = 0.f;
      for (int u = 0; u < 3; u++) for (int vv = 0; vv < 3; vv++) v += wd1[u*3+vv] * hdd[i+u][j+vv];
      h2[i][j] = v > 0.f ? v : 0.f;
    }
    float v = 0.f;
    for (int u = 0; u < 3; u++) for (int vv = 0; vv < 3; vv++) v += wd2[u*3+vv] * h2[u][vv];
    hdd3[s] = v > 0.f ? v : 0.f;
  }
}

// ---------------- K3: gates + weight synthesis -> wt[tap][o][c] (bf16) ---------------
__global__ __launch_bounds__(256) void k_wt(const float* __restrict__ convs,
                                            const float* __restrict__ w_pw2,
                                            const float* __restrict__ hdd3,
                                            ushort* __restrict__ wt) {
  int o = blockIdx.x;  // 0..767
  int tid = threadIdx.x;
  __shared__ float g[3];
  __shared__ __align__(16) ushort st[9 * C_IN];   // 13824 B
  if (tid < 3) {
    float v = 0.f;
    for (int s = 0; s < S_CH; s++)
      v += w_pw2[((size_t)tid * C_IN + o) * S_CH + s] * hdd3[s];
    g[tid] = 1.f / (1.f + __expf(-v));
  }
  __syncthreads();
  float g0 = g[0], g1 = g[1], g2 = g[2];
  const float* c0p = convs + (size_t)o * 6912;
  const float* c1p = convs + (size_t)(C_IN + o) * 6912;
  const float* c2p = convs + (size_t)(2 * C_IN + o) * 6912;
  for (int i = tid * 4; i < 6912; i += 1024) {
    floatx4 a = *(const floatx4*)(c0p + i);
    floatx4 b = *(const floatx4*)(c1p + i);
    floatx4 c = *(const floatx4*)(c2p + i);
#pragma unroll
    for (int j = 0; j < 4; j++) {
      int idx = i + j;
      int cch = idx / 9, tap = idx - cch * 9;
      st[tap * C_IN + cch] = f2bf(g0 * a[j] + g1 * b[j] + g2 * c[j]);
    }
  }
  __syncthreads();
  for (int i = tid; i < 864; i += 256) {        // 864 = 9*768/8 chunks of 16B
    int tap = i / 96, j = i - tap * 96;
    *(uint4v*)&wt[((size_t)(tap * C_IN + o)) * C_IN + j * 8] =
        *(const uint4v*)&st[tap * C_IN + j * 8];
  }
}

// ---------------- K4: main conv, MFMA 16x16x32 bf16 ----------------------------------
// R5: TLP retile. Same data-flow & schedule as the R1 champion (stage-next-then-
// compute, ONE __syncthreads per tap-phase, swizzled LDS, union-A), but:
//   * BN=64 (12 n-tiles) -> grid 120x12 = 1440 blocks = 5.6/CU (was 720 = 2.8/CU)
//   * 2 waves per block (128 thr), per-wave 64Mx64N (16 MFMA/phase preserved)
//   * LDS 32 KB (A 2x12KB + B 2x4KB) -> 5 blocks/CU resident; acc halves to 64 VGPR
// Theory: m102 scaling (m97 structure: 320 TF @1 blk/CU -> 833 @4) says the phase
// drain is covered by cross-block TLP, which grid 720 could not supply.
__global__ __launch_bounds__(128) void k_conv(const ushort* __restrict__ xTp,
                                              const ushort* __restrict__ wt,
                                              float* __restrict__ y) {
  __shared__ __align__(16) ushort Aun[2][768 * 8];   // 2 x 12288 B
  __shared__ __align__(16) ushort Bt[2][256 * 8];    // 2 x  4096 B  (32 KiB total)
  int tid = threadIdx.x;          // 0..127
  int lane = tid & 63;
  int quad = lane >> 4, l15 = lane & 15;
  int wave = tid >> 6;            // 0..1 == wave_m

  // XCD-chunked bijective swizzle (1440 % 8 == 0); wg = n_t*120 + m_t (n-major per XCD)
  int bid = blockIdx.x;
  int wg = (bid & 7) * 180 + (bid >> 3);
  int n_t = wg / 120, m_t = wg - n_t * 120;    // n_t 0..11, m_t 0..119
  int h0 = (m_t >> 3) << 3;    // 0..112 step 8
  int w0 = (m_t & 7) << 4;     // 0..112 step 16 (cols >=120 discarded)
  int n0 = n_t << 6;           // 0..704 step 64

  // A staging: slot t holds union pixel p=t>>2, source sub s=(t&3)^((p>>1)&3)
  uint a_off[6];
#pragma unroll
  for (int r = 0; r < 6; r++) {
    int t = r * 128 + tid;                       // 0..767
    int p = t >> 2; if (p > 179) p = 179;
    int sl = (t & 3) ^ ((p >> 1) & 3);
    int pr = p / 18, pc = p - pr * 18;           // union is 10 rows x 18 cols
    int pix = (h0 + pr) * WP + (w0 + pc);
    if (pix > PPIX - 1) pix = PPIX - 1;          // clamp: only affects discarded outputs
    a_off[r] = (uint)pix * C_IN + sl * 8;
  }
  // B staging: slot t -> row n=t>>2 (0..63), source sub s=(t&3)^((n>>1)&3)
  uint b_off[2];
#pragma unroll
  for (int r = 0; r < 2; r++) {
    int t = r * 128 + tid;                       // 0..255
    int n = t >> 2;
    int sl = (t & 3) ^ ((n >> 1) & 3);
    b_off[r] = (uint)(n0 + n) * C_IN + sl * 8;
  }
  // B read offsets (swizzled), constant per thread; both waves read all 64 n-rows
  int b_rd[4];
#pragma unroll
  for (int nt = 0; nt < 4; nt++) {
    int n = nt * 16 + l15;                       // 0..63
    b_rd[nt] = n * 32 + ((quad ^ ((n >> 1) & 3)) << 3);
  }
  int amh = wave * 4;                            // wave_m * 4
  int P0[4];
#pragma unroll
  for (int mt = 0; mt < 4; mt++) P0[mt] = (amh + mt) * 18 + l15;

  auto stageA = [&](int ncc, int na) {
#pragma unroll
    for (int r = 0; r < 6; r++)
      __builtin_amdgcn_global_load_lds(AS1(xTp + a_off[r] + ncc * 32),
                                       AS3(&Aun[na][(r * 128 + wave * 64) * 8]), 16, 0, 0);
  };
  auto stageB = [&](int ncc, int ntap, int nb) {
    const ushort* wb = wt + (size_t)ntap * C_IN * C_IN + ncc * 32;
#pragma unroll
    for (int r = 0; r < 2; r++)
      __builtin_amdgcn_global_load_lds(AS1(wb + b_off[r]),
                                       AS3(&Bt[nb][(r * 128 + wave * 64) * 8]), 16, 0, 0);
  };

  floatx4 acc[4][4];
#pragma unroll
  for (int i = 0; i < 4; i++)
#pragma unroll
    for (int j = 0; j < 4; j++) acc[i][j] = (floatx4){0.f, 0.f, 0.f, 0.f};

  // prologue: fill buffer 0 for (cc=0, tap=0)
  stageA(0, 0);
  stageB(0, 0, 0);
  __syncthreads();

  int pb = 0;
  for (int cc = 0; cc < 24; cc++) {
    int pa = cc & 1;
#pragma unroll
    for (int tap = 0; tap < 9; tap++) {
      const int kh = tap / 3, kw = tap % 3;      // compile-time (tap unrolled)
      // 1) issue next-iteration staging into the ALT buffers (overlaps with MFMA below)
      if (tap < 8) {
        stageB(cc, tap + 1, pb ^ 1);
      } else if (cc < 23) {
        stageB(cc + 1, 0, pb ^ 1);
        stageA(cc + 1, pa ^ 1);
      }
      // 2) fragments from CURRENT buffers (swizzled reads -> conflict-free)
      short8 bfr[4], af[4];
#pragma unroll
      for (int nt = 0; nt < 4; nt++) bfr[nt] = *(const short8*)&Bt[pb][b_rd[nt]];
#pragma unroll
      for (int mt = 0; mt < 4; mt++) {
        int p = P0[mt] + kh * 18 + kw;
        int idx = p * 32 + ((quad ^ ((p >> 1) & 3)) << 3);
        af[mt] = *(const short8*)&Aun[pa][idx];
      }
      // 3) MFMA cluster
#pragma unroll
      for (int mt = 0; mt < 4; mt++)
#pragma unroll
        for (int nt = 0; nt < 4; nt++)
          acc[mt][nt] = __builtin_amdgcn_mfma_f32_16x16x32_bf16(af[mt], bfr[nt], acc[mt][nt], 0, 0, 0);
      // 4) single barrier: drains this wave's staging + read-safety (R1 semantics)
      __syncthreads();
      pb ^= 1;
    }
  }

  // epilogue: D layout col(n)=lane&15, row(m)=quad*4+reg
  // tile row m = wave*64 + mt*16 + (quad*4+reg) -> h = h0+wave*4+mt, w = w0+quad*4+reg
#pragma unroll
  for (int mt = 0; mt < 4; mt++) {
    int h = h0 + wave * 4 + mt;
    int wbase = w0 + quad * 4;
    if (wbase < HW) {
#pragma unroll
      for (int nt = 0; nt < 4; nt++) {
        int n = n0 + nt * 16 + l15;
        *(floatx4*)&y[(size_t)n * PIX + h * HW + wbase] = acc[mt][nt];
      }
    }
  }
}

extern "C" void kernel_launch(void* const* d_in, const int* in_sizes, int n_in,
                              void* d_out, int out_size, void* d_ws, size_t ws_size,
                              hipStream_t stream) {
  const float* x     = (const float*)d_in[0];
  const float* convs = (const float*)d_in[1];
  const float* w_pw1 = (const float*)d_in[2];
  const float* w_dw1 = (const float*)d_in[3];
  const float* w_dw2 = (const float*)d_in[4];
  const float* w_pw2 = (const float*)d_in[5];
  float* y = (float*)d_out;
  char* ws = (char*)d_ws;
  float*  pooled = (float*)(ws + OFF_POOL);
  float*  hdd3   = (float*)(ws + OFF_HDD3);
  ushort* wt     = (ushort*)(ws + OFF_WT);
  ushort* xTp    = (ushort*)(ws + OFF_XTP);

  hipLaunchKernelGGL(k_pad_transpose, dim3(122, 3), dim3(256), 0, stream, x, xTp);
  hipLaunchKernelGGL(k_pool,          dim3(768),    dim3(256), 0, stream, x, pooled);
  hipLaunchKernelGGL(k_route,         dim3(48),     dim3(256), 0, stream, pooled, w_pw1, w_dw1, w_dw2, hdd3);
  hipLaunchKernelGGL(k_wt,            dim3(768),    dim3(256), 0, stream, convs, w_pw2, hdd3, wt);
  hipLaunchKernelGGL(k_conv,          dim3(1440),   dim3(128), 0, stream, xTp, wt, y);
}

// Round 7
// 329.234 us; speedup vs baseline: 1.4292x; 1.2482x over previous
//
#include <hip/hip_runtime.h>
#include <hip/hip_bf16.h>
#include <cstdint>
#include <cstddef>

#define C_IN 768
#define HW 120
#define WP 122
#define PIX (HW*HW)       // 14400
#define PPIX (WP*WP)      // 14884
#define S_CH 48
#define CCH 256           // channel chunk for transpose
#define LSTR 257          // LDS row stride (ushorts), 257 % 32 == 1 -> conflict-free

// ws layout (bytes)
#define OFF_POOL 0                    // 768*51*4 = 156672
#define OFF_HDD3 163840               // 48 floats
#define OFF_WT   262144               // 9*768*768*2 = 10616832
#define OFF_XTP  10878976             // 14884*768*2 = 22861824 ; end ~33.7MB

typedef __attribute__((ext_vector_type(8))) short short8;
typedef __attribute__((ext_vector_type(4))) float floatx4;
typedef __attribute__((ext_vector_type(4))) uint uint4v;

#define AS3(p) ((__attribute__((address_space(3))) uint*)(p))
#define AS1(p) ((const __attribute__((address_space(1))) uint*)(p))

__device__ inline ushort f2bf(float f) {
  union { float f; uint i; } v; v.f = f;
  uint r = v.i + 0x7FFF + ((v.i >> 16) & 1);   // round-to-nearest-even
  return (ushort)(r >> 16);
}

// PyTorch bicubic(3->5), a=-0.75, align_corners=False, border-replicate
__device__ __constant__ float M35[5][3] = {
  { 1.096f, -0.096f,  0.000f },
  { 0.612f,  0.460f, -0.072f },
  { 0.000f,  1.000f,  0.000f },
  {-0.072f,  0.460f,  0.612f },
  { 0.000f, -0.096f,  1.096f },
};

// ---------------- K0: zero-pad + transpose x (C,H,W) f32 -> xTp (122*122, C) bf16 ----
__global__ __launch_bounds__(256) void k_pad_transpose(const float* __restrict__ x,
                                                       ushort* __restrict__ xTp) {
  int ph = blockIdx.x;          // padded row 0..121
  int c0 = blockIdx.y * CCH;    // 0, 256, 512
  int tid = threadIdx.x;
  ushort* rowbase = xTp + (size_t)ph * WP * C_IN;
  if (ph == 0 || ph == WP - 1) {
    uint4v z = {0, 0, 0, 0};
    for (int i = tid; i < WP * (CCH / 8); i += 256) {
      int w = i / (CCH / 8), j = i % (CCH / 8);
      *(uint4v*)&rowbase[(size_t)w * C_IN + c0 + j * 8] = z;
    }
    return;
  }
  int h = ph - 1;
  __shared__ ushort T[HW * LSTR];   // 120*257*2 = 61680 B
  int wave = tid >> 6, lane = tid & 63;
  for (int k = 0; k < 64; k++) {
    int cl = wave * 64 + k;                       // local channel 0..255
    const float* src = x + (size_t)(c0 + cl) * PIX + h * HW;
    if (lane < 60) {
      float vx = src[2 * lane], vy = src[2 * lane + 1];
      T[(2 * lane) * LSTR + cl]     = f2bf(vx);
      T[(2 * lane + 1) * LSTR + cl] = f2bf(vy);
    }
  }
  __syncthreads();
  if (tid < 128) {
    *(uint*)&rowbase[c0 + 2 * tid] = 0;
    *(uint*)&rowbase[(size_t)(WP - 1) * C_IN + c0 + 2 * tid] = 0;
  }
  for (int idx = tid; idx < HW * (CCH / 2); idx += 256) {
    int w = idx >> 7, pr = idx & 127;
    uint a = T[w * LSTR + 2 * pr];
    uint b = T[w * LSTR + 2 * pr + 1];
    *(uint*)&rowbase[(size_t)(1 + w) * C_IN + c0 + 2 * pr] = a | (b << 16);
  }
}

// ---------------- K1: pooling per channel: a1, a3u (bicubic), a5 -> pooled[c][51] -----
__global__ __launch_bounds__(256) void k_pool(const float* __restrict__ x,
                                              float* __restrict__ pooled) {
  int c = blockIdx.x;
  int tid = threadIdx.x;
  __shared__ float fine[225];   // 15x15 grid of 8x8 block sums
  __shared__ float s3[9], a3v[9], a5v[25];
  if (tid < 225) {
    int fr = tid / 15, fc = tid % 15;
    const float* base = x + (size_t)c * PIX + fr * 8 * HW + fc * 8;
    float s = 0.f;
#pragma unroll
    for (int r = 0; r < 8; r++) {
      floatx4 a = *(const floatx4*)(base + r * HW);
      floatx4 b = *(const floatx4*)(base + r * HW + 4);
#pragma unroll
      for (int j = 0; j < 4; j++) s += a[j] + b[j];
    }
    fine[tid] = s;
  }
  __syncthreads();
  if (tid < 9) {
    int i = tid / 3, j = tid % 3;
    float s = 0.f;
    for (int a = 0; a < 5; a++) for (int b = 0; b < 5; b++) s += fine[(i*5+a)*15 + j*5+b];
    s3[tid] = s; a3v[tid] = s / 1600.f;
  } else if (tid >= 32 && tid < 57) {
    int t = tid - 32; int p = t / 5, q = t % 5;
    float s = 0.f;
    for (int a = 0; a < 3; a++) for (int b = 0; b < 3; b++) s += fine[(p*3+a)*15 + q*3+b];
    a5v[t] = s / 576.f;
  }
  __syncthreads();
  float* out = pooled + c * 51;
  if (tid == 63) {
    float tot = 0.f;
    for (int k = 0; k < 9; k++) tot += s3[k];
    out[0] = tot / 14400.f;
  }
  if (tid < 25) {
    int p = tid / 5, q = tid % 5;
    float s = 0.f;
    for (int i = 0; i < 3; i++) for (int j = 0; j < 3; j++)
      s += M35[p][i] * M35[q][j] * a3v[i*3+j];
    out[1 + tid] = s;
    out[26 + tid] = a5v[tid];
  }
}

// ---------------- K2: routing MLP -> hdd3[48] ----------------------------------------
__global__ __launch_bounds__(256) void k_route(const float* __restrict__ pooled,
                                               const float* __restrict__ w_pw1,
                                               const float* __restrict__ w_dw1,
                                               const float* __restrict__ w_dw2,
                                               float* __restrict__ hdd3) {
  int s = blockIdx.x;  // 0..47
  int tid = threadIdx.x;
  __shared__ float red[26][256];
  float acc[25]; float accw1 = 0.f;
#pragma unroll
  for (int q = 0; q < 25; q++) acc[q] = 0.f;
  for (int c = tid; c < C_IN; c += 256) {
    const float* pl = pooled + c * 51;
    float w1 = w_pw1[(size_t)s * 3 * C_IN + c];
    float w2 = w_pw1[(size_t)s * 3 * C_IN + C_IN + c];
    float w3 = w_pw1[(size_t)s * 3 * C_IN + 2 * C_IN + c];
    accw1 += w1 * pl[0];
#pragma unroll
    for (int q = 0; q < 25; q++) acc[q] += w2 * pl[1 + q] + w3 * pl[26 + q];
  }
#pragma unroll
  for (int q = 0; q < 25; q++) red[q][tid] = acc[q];
  red[25][tid] = accw1;
  for (int st = 128; st; st >>= 1) {
    __syncthreads();
    if (tid < st)
      for (int q = 0; q < 26; q++) red[q][tid] += red[q][tid + st];
  }
  __syncthreads();
  if (tid == 0) {
    float hdd[5][5];
    for (int p = 0; p < 5; p++) for (int q = 0; q < 5; q++) {
      float v = red[p*5+q][0] + red[25][0];
      hdd[p][q] = v > 0.f ? v : 0.f;
    }
    float wd1[9], wd2[9];
    for (int i = 0; i < 9; i++) { wd1[i] = w_dw1[s*9 + i]; wd2[i] = w_dw2[s*9 + i]; }
    float h2[3][3];
    for (int i = 0; i < 3; i++) for (int j = 0; j < 3; j++) {
      float v = 0.f;
      for (int u = 0; u < 3; u++) for (int vv = 0; vv < 3; vv++) v += wd1[u*3+vv] * hdd[i+u][j+vv];
      h2[i][j] = v > 0.f ? v : 0.f;
    }
    float v = 0.f;
    for (int u = 0; u < 3; u++) for (int vv = 0; vv < 3; vv++) v += wd2[u*3+vv] * h2[u][vv];
    hdd3[s] = v > 0.f ? v : 0.f;
  }
}

// ---------------- K3: gates + weight synthesis -> wt[tap][o][c] (bf16) ---------------
__global__ __launch_bounds__(256) void k_wt(const float* __restrict__ convs,
                                            const float* __restrict__ w_pw2,
                                            const float* __restrict__ hdd3,
                                            ushort* __restrict__ wt) {
  int o = blockIdx.x;  // 0..767
  int tid = threadIdx.x;
  __shared__ float g[3];
  __shared__ __align__(16) ushort st[9 * C_IN];   // 13824 B
  if (tid < 3) {
    float v = 0.f;
    for (int s = 0; s < S_CH; s++)
      v += w_pw2[((size_t)tid * C_IN + o) * S_CH + s] * hdd3[s];
    g[tid] = 1.f / (1.f + __expf(-v));
  }
  __syncthreads();
  float g0 = g[0], g1 = g[1], g2 = g[2];
  const float* c0p = convs + (size_t)o * 6912;
  const float* c1p = convs + (size_t)(C_IN + o) * 6912;
  const float* c2p = convs + (size_t)(2 * C_IN + o) * 6912;
  for (int i = tid * 4; i < 6912; i += 1024) {
    floatx4 a = *(const floatx4*)(c0p + i);
    floatx4 b = *(const floatx4*)(c1p + i);
    floatx4 c = *(const floatx4*)(c2p + i);
#pragma unroll
    for (int j = 0; j < 4; j++) {
      int idx = i + j;
      int cch = idx / 9, tap = idx - cch * 9;
      st[tap * C_IN + cch] = f2bf(g0 * a[j] + g1 * b[j] + g2 * c[j]);
    }
  }
  __syncthreads();
  for (int i = tid; i < 864; i += 256) {        // 864 = 9*768/8 chunks of 16B
    int tap = i / 96, j = i - tap * 96;
    *(uint4v*)&wt[((size_t)(tap * C_IN + o)) * C_IN + j * 8] =
        *(const uint4v*)&st[tap * C_IN + j * 8];
  }
}

// ---------------- K4: main conv, MFMA 16x16x32 bf16 ----------------------------------
// R7: m201-template port. 240 blocks (10h x 8w x 3n) = 1/CU, 512 thr = 8 waves (2Mx4N),
// per-wave 96x64, acc 6x4. K-tile = tap x 64ch (108 tiles), 2 FAT phases per K-tile
// (24 MFMA + 10 ds_read each; MFMA ~930cyc/CU = LDS ~960cyc/CU balanced).
//   * B: ring of 4 half-buffers (256n x 32ch = 16KB): read half at phase p, restage
//     that slot at phase p+1 (one barrier between -> WAR safe). slot = (2g+ks)&3.
//   * A: 14x18-px union (both ks halves), double-buffered per 64ch chunk; staged
//     during taps 4-5 (4 gloads/wave) for cc+1.
//   * ONE raw s_barrier per phase (216 total); per-wave counted WAITV at ph(g,2)
//     certifies tile g+1 (staged >=1 fat phase earlier -> no-op in steady state).
//     Cross-wave RAW: certify-at-(g-1,2) + barrier precedes all reads of g.
//   * LDS 128 KB (the m201 budget): A 2x32KB + B 4x16KB.
#define WAITV(N) asm volatile("s_waitcnt vmcnt(" #N ")" ::: "memory")
#define FENCE()  asm volatile("" ::: "memory")

// one phase: [WAITV?][ds_read frags][stage issues][fence][barrier][sched_bar][24 MFMA]
#define PHASE(WSTMT, KS, RSLOT, PAv, KH, KW, STAGES) do {                      \
    WSTMT;                                                                     \
    short8 bfr[4], af[6];                                                      \
    _Pragma("unroll")                                                          \
    for (int nt = 0; nt < 4; nt++)                                             \
      bfr[nt] = *(const short8*)&Bt[RSLOT][b_rd[nt]];                          \
    _Pragma("unroll")                                                          \
    for (int mt = 0; mt < 6; mt++) {                                           \
      int u_ = P0[mt] + ((KH) * 18 + (KW));                                    \
      int idx_ = u_ * 32 + ((quad ^ ((u_ >> 1) & 3)) << 3);                    \
      af[mt] = *(const short8*)&Aun[PAv][KS][idx_];                            \
    }                                                                          \
    STAGES;                                                                    \
    FENCE();                                                                   \
    __builtin_amdgcn_s_barrier();                                              \
    __builtin_amdgcn_sched_barrier(0);                                         \
    __builtin_amdgcn_s_setprio(1);                                             \
    _Pragma("unroll")                                                          \
    for (int mt = 0; mt < 6; mt++)                                             \
      _Pragma("unroll")                                                        \
      for (int nt = 0; nt < 4; nt++)                                           \
        acc[mt][nt] = __builtin_amdgcn_mfma_f32_16x16x32_bf16(af[mt], bfr[nt], \
                                                              acc[mt][nt], 0, 0, 0); \
    __builtin_amdgcn_s_setprio(0);                                             \
  } while (0)

// full cc body (18 phases). P = parity offset (0 even cc, 2 odd). PAv = cc&1.
// (t,1) reads (g,ks0) slot (2t+P)&3, stages (g+1,ks1) -> slot (2t+3+P)&3.
// (t,2) reads (g,ks1) slot (2t+1+P)&3, certifies g+1, stages (g+2,ks0) -> (2t+P)&3.
// A for cc+1 staged rounds 0..3 at (4,1),(4,2),(5,1),(5,2) (WAITV 1 there).
#define CCB(ccv, P, PAv) do { const int cc_ = (ccv);                               \
    PHASE(;,        0, ((0+P)&3),  PAv, 0,0, { SB(1, cc_, 1, ((3+P)&3)); });        \
    PHASE(WAITV(0), 1, ((1+P)&3),  PAv, 0,0, { SB(2, cc_, 0, ((0+P)&3)); });        \
    PHASE(;,        0, ((2+P)&3),  PAv, 0,1, { SB(2, cc_, 1, ((5+P)&3)); });        \
    PHASE(WAITV(0), 1, ((3+P)&3),  PAv, 0,1, { SB(3, cc_, 0, ((2+P)&3)); });        \
    PHASE(;,        0, ((4+P)&3),  PAv, 0,2, { SB(3, cc_, 1, ((7+P)&3)); });        \
    PHASE(WAITV(0), 1, ((5+P)&3),  PAv, 0,2, { SB(4, cc_, 0, ((4+P)&3)); });        \
    PHASE(;,        0, ((6+P)&3),  PAv, 1,0, { SB(4, cc_, 1, ((9+P)&3)); });        \
    PHASE(WAITV(0), 1, ((7+P)&3),  PAv, 1,0, { SB(5, cc_, 0, ((6+P)&3)); });        \
    PHASE(;,        0, ((8+P)&3),  PAv, 1,1, { SB(5, cc_, 1, ((11+P)&3)); SA(cc_+1, (PAv)^1, 0); }); \
    PHASE(WAITV(1), 1, ((9+P)&3),  PAv, 1,1, { SB(6, cc_, 0, ((8+P)&3));  SA(cc_+1, (PAv)^1, 1); }); \
    PHASE(;,        0, ((10+P)&3), PAv, 1,2, { SB(6, cc_, 1, ((13+P)&3)); SA(cc_+1, (PAv)^1, 2); }); \
    PHASE(WAITV(1), 1, ((11+P)&3), PAv, 1,2, { SB(7, cc_, 0, ((10+P)&3)); SA(cc_+1, (PAv)^1, 3); }); \
    PHASE(;,        0, ((12+P)&3), PAv, 2,0, { SB(7, cc_, 1, ((15+P)&3)); });       \
    PHASE(WAITV(0), 1, ((13+P)&3), PAv, 2,0, { SB(8, cc_, 0, ((12+P)&3)); });       \
    PHASE(;,        0, ((14+P)&3), PAv, 2,1, { SB(8, cc_, 1, ((17+P)&3)); });       \
    PHASE(WAITV(0), 1, ((15+P)&3), PAv, 2,1, { SB(0, cc_+1, 0, ((14+P)&3)); });     \
    PHASE(;,        0, ((16+P)&3), PAv, 2,2, { SB(0, cc_+1, 1, ((19+P)&3)); });     \
    PHASE(WAITV(0), 1, ((17+P)&3), PAv, 2,2, { SB(1, cc_+1, 0, ((16+P)&3)); });     \
  } while (0)

// cc=11 tail: no A stages, no stages past g=107, no WAITV at (8,2).
#define CCB11() do { const int cc_ = 11;                                           \
    PHASE(;,        0, ((0+2)&3),  1, 0,0, { SB(1, cc_, 1, ((3+2)&3)); });          \
    PHASE(WAITV(0), 1, ((1+2)&3),  1, 0,0, { SB(2, cc_, 0, ((0+2)&3)); });          \
    PHASE(;,        0, ((2+2)&3),  1, 0,1, { SB(2, cc_, 1, ((5+2)&3)); });          \
    PHASE(WAITV(0), 1, ((3+2)&3),  1, 0,1, { SB(3, cc_, 0, ((2+2)&3)); });          \
    PHASE(;,        0, ((4+2)&3),  1, 0,2, { SB(3, cc_, 1, ((7+2)&3)); });          \
    PHASE(WAITV(0), 1, ((5+2)&3),  1, 0,2, { SB(4, cc_, 0, ((4+2)&3)); });          \
    PHASE(;,        0, ((6+2)&3),  1, 1,0, { SB(4, cc_, 1, ((9+2)&3)); });          \
    PHASE(WAITV(0), 1, ((7+2)&3),  1, 1,0, { SB(5, cc_, 0, ((6+2)&3)); });          \
    PHASE(;,        0, ((8+2)&3),  1, 1,1, { SB(5, cc_, 1, ((11+2)&3)); });         \
    PHASE(WAITV(0), 1, ((9+2)&3),  1, 1,1, { SB(6, cc_, 0, ((8+2)&3)); });          \
    PHASE(;,        0, ((10+2)&3), 1, 1,2, { SB(6, cc_, 1, ((13+2)&3)); });         \
    PHASE(WAITV(0), 1, ((11+2)&3), 1, 1,2, { SB(7, cc_, 0, ((10+2)&3)); });         \
    PHASE(;,        0, ((12+2)&3), 1, 2,0, { SB(7, cc_, 1, ((15+2)&3)); });         \
    PHASE(WAITV(0), 1, ((13+2)&3), 1, 2,0, { SB(8, cc_, 0, ((12+2)&3)); });         \
    PHASE(;,        0, ((14+2)&3), 1, 2,1, { SB(8, cc_, 1, ((17+2)&3)); });         \
    PHASE(WAITV(0), 1, ((15+2)&3), 1, 2,1, { ; });                                  \
    PHASE(;,        0, ((16+2)&3), 1, 2,2, { ; });                                  \
    PHASE(;,        1, ((17+2)&3), 1, 2,2, { ; });                                  \
  } while (0)

__global__ __launch_bounds__(512, 2) void k_conv(const ushort* __restrict__ xTp,
                                                 const ushort* __restrict__ wt,
                                                 float* __restrict__ y) {
  __shared__ __align__(16) ushort Aun[2][2][8192];   // [pa][ks][256 rows x 32ch] = 64 KB
  __shared__ __align__(16) ushort Bt[4][8192];       // 4 half-slots x 16 KB = 64 KB
  int tid = threadIdx.x;          // 0..511
  int lane = tid & 63;
  int quad = lane >> 4, l15 = lane & 15;
  int wave = tid >> 6;            // 0..7
  int wm = wave >> 2, wn = wave & 3;

  // XCD-chunked bijective swizzle (240 % 8 == 0); wg = n_t*80 + m_t (n-major per XCD)
  int bid = blockIdx.x;
  int wg = (bid & 7) * 30 + (bid >> 3);
  int n_t = wg / 80, m_t = wg - n_t * 80;   // n_t 0..2, m_t 0..79
  int h0 = (m_t >> 3) * 12;    // 0..108 step 12 (exact)
  int w0 = (m_t & 7) << 4;     // 0..112 step 16 (cols >=120 discarded)
  int n0 = n_t << 8;           // 0, 256, 512

  // A staging offsets: round r in 0..3, slot t=r*512+tid: ks=t>>10, row u=(t>>2)&255,
  // src sub-slot sl=(t&3)^((u>>1)&3); union 14 rows x 18 cols (clamped)
  size_t a_off[4];
#pragma unroll
  for (int r = 0; r < 4; r++) {
    int t = r * 512 + tid;
    int ks = t >> 10;
    int u = (t >> 2) & 255; if (u > 251) u = 251;
    int sl = (t & 3) ^ ((u >> 1) & 3);
    int ur = u / 18, uc = u - ur * 18;
    int pix = (h0 + ur) * WP + (w0 + uc);
    if (pix > PPIX - 1) pix = PPIX - 1;            // clamp: only feeds discarded outputs
    a_off[r] = (size_t)pix * C_IN + ks * 32 + sl * 8;
  }
  // B staging offsets: round r in 0..1, t=r*512+tid: row n=t>>2 (0..255),
  // sub-slot sl=(t&3)^((n>>1)&3)
  size_t b_off[2];
#pragma unroll
  for (int r = 0; r < 2; r++) {
    int t = r * 512 + tid;
    int n = t >> 2;
    int sl = (t & 3) ^ ((n >> 1) & 3);
    b_off[r] = (size_t)(n0 + n) * C_IN + sl * 8;
  }
  // B frag read offsets (swizzled, per thread)
  int b_rd[4];
#pragma unroll
  for (int nt = 0; nt < 4; nt++) {
    int n = wn * 64 + nt * 16 + l15;               // 0..255
    b_rd[nt] = n * 32 + ((quad ^ ((n >> 1) & 3)) << 3);
  }
  // A frag row bases: frag mt row = wm*6+mt, lane col = l15
  int P0[6];
#pragma unroll
  for (int mt = 0; mt < 6; mt++) P0[mt] = (wm * 6 + mt) * 18 + l15;

  // stage one B half (tap gtap of chunk gcc, ks half) into ring slot
  auto SB = [&](int gtap, int gcc, int ks, int slot) {
    const ushort* src = wt + (size_t)gtap * (C_IN * C_IN) + gcc * 64 + ks * 32;
#pragma unroll
    for (int r = 0; r < 2; r++)
      __builtin_amdgcn_global_load_lds(AS1(src + b_off[r]),
                                       AS3(&Bt[slot][r * 4096 + wave * 512]), 16, 0, 0);
  };
  // stage one A round (r in 0..3) of chunk gcc into buffer pa
  auto SA = [&](int gcc, int pa, int r) {
    __builtin_amdgcn_global_load_lds(AS1(xTp + a_off[r] + gcc * 64),
                                     AS3(&Aun[pa][0][0] + r * 4096 + wave * 512), 16, 0, 0);
  };

  floatx4 acc[6][4];
#pragma unroll
  for (int i = 0; i < 6; i++)
#pragma unroll
    for (int j = 0; j < 4; j++) acc[i][j] = (floatx4){0.f, 0.f, 0.f, 0.f};

  // prologue: B(g0,ks0)->slot0, B(g0,ks1)->slot1, A(cc0)->pa0, B(g1,ks0)->slot2;
  // certify all but the last B half; one barrier publishes.
  SB(0, 0, 0, 0);
  SB(0, 0, 1, 1);
  SA(0, 0, 0); SA(0, 0, 1); SA(0, 0, 2); SA(0, 0, 3);
  SB(1, 0, 0, 2);
  WAITV(2);
  FENCE();
  __builtin_amdgcn_s_barrier();

  for (int cc = 0; cc < 10; cc += 2) {
    CCB(cc,     0, 0);
    CCB(cc + 1, 2, 1);
  }
  CCB(10, 0, 0);
  CCB11();

  // epilogue: D layout col(n)=lane&15, row(m)=quad*4+reg
  // tile M = wm*96 + mt*16 + quad*4+j -> h = h0 + wm*6 + mt, w = w0 + quad*4 + j
#pragma unroll
  for (int mt = 0; mt < 6; mt++) {
    int h = h0 + wm * 6 + mt;
    int wbase = w0 + quad * 4;
    if (wbase < HW) {
#pragma unroll
      for (int nt = 0; nt < 4; nt++) {
        int n = n0 + wn * 64 + nt * 16 + l15;
        *(floatx4*)&y[(size_t)n * PIX + h * HW + wbase] = acc[mt][nt];
      }
    }
  }
}

extern "C" void kernel_launch(void* const* d_in, const int* in_sizes, int n_in,
                              void* d_out, int out_size, void* d_ws, size_t ws_size,
                              hipStream_t stream) {
  const float* x     = (const float*)d_in[0];
  const float* convs = (const float*)d_in[1];
  const float* w_pw1 = (const float*)d_in[2];
  const float* w_dw1 = (const float*)d_in[3];
  const float* w_dw2 = (const float*)d_in[4];
  const float* w_pw2 = (const float*)d_in[5];
  float* y = (float*)d_out;
  char* ws = (char*)d_ws;
  float*  pooled = (float*)(ws + OFF_POOL);
  float*  hdd3   = (float*)(ws + OFF_HDD3);
  ushort* wt     = (ushort*)(ws + OFF_WT);
  ushort* xTp    = (ushort*)(ws + OFF_XTP);

  hipLaunchKernelGGL(k_pad_transpose, dim3(122, 3), dim3(256), 0, stream, x, xTp);
  hipLaunchKernelGGL(k_pool,          dim3(768),    dim3(256), 0, stream, x, pooled);
  hipLaunchKernelGGL(k_route,         dim3(48),     dim3(256), 0, stream, pooled, w_pw1, w_dw1, w_dw2, hdd3);
  hipLaunchKernelGGL(k_wt,            dim3(768),    dim3(256), 0, stream, convs, w_pw2, hdd3, wt);
  hipLaunchKernelGGL(k_conv,          dim3(240),    dim3(512), 0, stream, xTp, wt, y);
}